// Round 10
// baseline (128.746 us; speedup 1.0000x reference)
//
#include <hip/hip_runtime.h>

#define NB   2
#define NCO  8
#define NCI  8
#define ND   8
#define NGH  16
#define NGW  16
#define NH   512
#define NW   512
#define HW   (NH * NW)
#define CSTR 132   // LDS column stride in floats: 128 data + 4 pad (4 mod 32 banks -> conflict-free)
#define TBL  (17 * CSTR)

// ---- grid staging helpers: 2048 table entries / 256 threads = 8 per thread ----
__device__ __forceinline__ void grid_load(const float* __restrict__ gbase, int tid, int cy,
                                          float (&ga)[8], float (&gb)[8])
{
    #pragma unroll
    for (int it = 0; it < 8; ++it) {
        int i   = tid + it * 256;          // 0..2047
        int col = i & 15;
        int j   = i >> 4;                  // co*16 + k*8 + z
        int co  = j >> 4, k = (j >> 3) & 1, z = j & 7;
        const float* gp = gbase + ((((size_t)co * 2 + k) * ND + z) * NGH + cy) * NGW + col;
        ga[it] = gp[0];
        gb[it] = gp[NGW];
    }
}

__device__ __forceinline__ void grid_stage(float* __restrict__ buf, int tid, float wy,
                                           const float (&ga)[8], const float (&gb)[8])
{
    #pragma unroll
    for (int it = 0; it < 8; ++it) {
        int i   = tid + it * 256;
        int col = i & 15;
        int j   = i >> 4;
        int k   = (j >> 3) & 1;
        float v = ga[it] * (1.f - wy) + gb[it] * wy;
        if (k) v *= 0.125f;                // fold bias mean (1/8)
        buf[col * CSTR + j] = v;
    }
}

// ---- z-tent accumulation for 2 px ----
__device__ __forceinline__ void tent8(const float2 (&g2)[8], const float2 (&v2)[8],
                                      float (&S0)[2][8], float (&S1)[2][8])
{
    #pragma unroll
    for (int p = 0; p < 2; ++p)
        #pragma unroll
        for (int z = 0; z < 8; ++z) { S0[p][z] = 0.f; S1[p][z] = 0.f; }
    #pragma unroll
    for (int ci = 0; ci < NCI; ++ci) {
        #pragma unroll
        for (int p = 0; p < 2; ++p) {
            float g = p ? g2[ci].y : g2[ci].x;
            float v = p ? v2[ci].y : v2[ci].x;
            float zp = fminf(fmaxf(g * 7.0f, 0.0f), 7.0f);
            #pragma unroll
            for (int z = 0; z < 8; ++z) {
                float a = fmaxf(0.0f, 1.0f - fabsf(zp - (float)z));
                S0[p][z] = fmaf(a, v, S0[p][z]);
                S1[p][z] += a;
            }
        }
    }
}

// ---- 3-column epilogue for 2 px, 8 co planes ----
__device__ __forceinline__ void epilogue8(
    const float* __restrict__ tb,                 // sg buffer + c0*CSTR
    const float (&S0)[2][8], const float (&S1)[2][8],
    float wA0, float wA1, float wB0, float wB1, float wC0, float wC1,
    float* __restrict__ outp)                     // out + batch/row/px offset
{
    #pragma unroll 1
    for (int co = 0; co < NCO; ++co) {
        float dA0, dA1, dB0, dB1, dC0, dC1;
        #pragma unroll
        for (int c = 0; c < 3; ++c) {
            const float* q = tb + c * CSTR + co * 16;
            const float4 a0 = *(const float4*)(q + 0);
            const float4 a1 = *(const float4*)(q + 4);
            const float4 a2 = *(const float4*)(q + 8);
            const float4 a3 = *(const float4*)(q + 12);
            float d0, d1;
            d0 = S0[0][0] * a0.x;              d1 = S0[1][0] * a0.x;
            d0 = fmaf(S0[0][1], a0.y, d0);     d1 = fmaf(S0[1][1], a0.y, d1);
            d0 = fmaf(S0[0][2], a0.z, d0);     d1 = fmaf(S0[1][2], a0.z, d1);
            d0 = fmaf(S0[0][3], a0.w, d0);     d1 = fmaf(S0[1][3], a0.w, d1);
            d0 = fmaf(S0[0][4], a1.x, d0);     d1 = fmaf(S0[1][4], a1.x, d1);
            d0 = fmaf(S0[0][5], a1.y, d0);     d1 = fmaf(S0[1][5], a1.y, d1);
            d0 = fmaf(S0[0][6], a1.z, d0);     d1 = fmaf(S0[1][6], a1.z, d1);
            d0 = fmaf(S0[0][7], a1.w, d0);     d1 = fmaf(S0[1][7], a1.w, d1);
            d0 = fmaf(S1[0][0], a2.x, d0);     d1 = fmaf(S1[1][0], a2.x, d1);
            d0 = fmaf(S1[0][1], a2.y, d0);     d1 = fmaf(S1[1][1], a2.y, d1);
            d0 = fmaf(S1[0][2], a2.z, d0);     d1 = fmaf(S1[1][2], a2.z, d1);
            d0 = fmaf(S1[0][3], a2.w, d0);     d1 = fmaf(S1[1][3], a2.w, d1);
            d0 = fmaf(S1[0][4], a3.x, d0);     d1 = fmaf(S1[1][4], a3.x, d1);
            d0 = fmaf(S1[0][5], a3.y, d0);     d1 = fmaf(S1[1][5], a3.y, d1);
            d0 = fmaf(S1[0][6], a3.z, d0);     d1 = fmaf(S1[1][6], a3.z, d1);
            d0 = fmaf(S1[0][7], a3.w, d0);     d1 = fmaf(S1[1][7], a3.w, d1);
            if (c == 0)      { dA0 = d0; dA1 = d1; }
            else if (c == 1) { dB0 = d0; dB1 = d1; }
            else             { dC0 = d0; dC1 = d1; }
        }
        float r0 = wA0 * dA0;
        r0 = fmaf(wB0, dB0, r0);
        r0 = fmaf(wC0, dC0, r0);
        float r1 = wA1 * dA1;
        r1 = fmaf(wB1, dB1, r1);
        r1 = fmaf(wC1, dC1, r1);
        *(float2*)(outp + (size_t)co * HW) = make_float2(r0, r1);
    }
}

// One 256-thread block per row index; iter A = batch 0, iter B = batch 1
// (same row -> cy/wy/c0/x-weights shared). Double-buffered LDS table;
// software pipeline: batch-1 guide/input prefetched before epilogue A
// (latency covered by epilogue A's LDS+VALU), grid-B loads covered by tent B.
__global__ __launch_bounds__(256, 4) void bslice_kernel(
    const float* __restrict__ grid,
    const float* __restrict__ guide,
    const float* __restrict__ inp,
    float* __restrict__ out)
{
    const int tid = threadIdx.x;
    const int y   = blockIdx.x;

    const float step = 15.0f / 511.0f;
    const float yp = (float)y * step;
    const int   cy = min((int)yp, NGH - 2);
    const float wy = yp - (float)cy;

    const int px0 = tid * 2;
    const float xp0 = (float)px0 * step;
    const int   c0  = min((int)xp0, NGW - 2);
    const float u0  = xp0 - (float)c0;
    const float u1  = u0 + step;
    const float wA0 = fmaxf(0.f, 1.f - u0), wA1 = fmaxf(0.f, 1.f - u1);
    const float wB0 = 1.f - fabsf(u0 - 1.f), wB1 = 1.f - fabsf(u1 - 1.f);
    const float wC0 = fmaxf(0.f, u0 - 1.f), wC1 = fmaxf(0.f, u1 - 1.f);

    __shared__ float sg[2][TBL];
    if (tid < 128) {                       // zero pad column 16 of both buffers
        sg[0][16 * CSTR + tid] = 0.f;
        sg[1][16 * CSTR + tid] = 0.f;
    }

    const size_t rowoff = (size_t)y * NW + px0;

    // ---- iter A (batch 0): loads ----
    float ga[8], gb[8];
    grid_load(grid, tid, cy, ga, gb);
    float2 g2[8], v2[8];
    #pragma unroll
    for (int ci = 0; ci < NCI; ++ci) {
        g2[ci] = *(const float2*)(guide + (size_t)ci * HW + rowoff);
        v2[ci] = *(const float2*)(inp   + (size_t)ci * HW + rowoff);
    }

    float S0A[2][8], S1A[2][8];
    tent8(g2, v2, S0A, S1A);
    grid_stage(sg[0], tid, wy, ga, gb);
    __syncthreads();

    // ---- prefetch batch-1 guide/input (in flight during epilogue A) ----
    const size_t in1 = (size_t)NCI * HW + rowoff;
    float2 g2B[8], v2B[8];
    #pragma unroll
    for (int ci = 0; ci < NCI; ++ci) {
        g2B[ci] = *(const float2*)(guide + in1 + (size_t)ci * HW);
        v2B[ci] = *(const float2*)(inp   + in1 + (size_t)ci * HW);
    }

    // ---- epilogue A -> batch-0 output ----
    epilogue8(&sg[0][c0 * CSTR], S0A, S1A, wA0, wA1, wB0, wB1, wC0, wC1,
              out + rowoff);

    // ---- iter B (batch 1): grid loads covered by tent B's VALU ----
    float gaB[8], gbB[8];
    grid_load(grid + (size_t)NCO * 2 * ND * NGH * NGW, tid, cy, gaB, gbB);

    float S0B[2][8], S1B[2][8];
    tent8(g2B, v2B, S0B, S1B);
    grid_stage(sg[1], tid, wy, gaB, gbB);
    __syncthreads();

    // ---- epilogue B -> batch-1 output ----
    epilogue8(&sg[1][c0 * CSTR], S0B, S1B, wA0, wA1, wB0, wB1, wC0, wC1,
              out + (size_t)NCO * HW + rowoff);
}

extern "C" void kernel_launch(void* const* d_in, const int* in_sizes, int n_in,
                              void* d_out, int out_size, void* d_ws, size_t ws_size,
                              hipStream_t stream) {
    const float* grid  = (const float*)d_in[0];
    const float* guide = (const float*)d_in[1];
    const float* inp   = (const float*)d_in[2];
    float* out = (float*)d_out;

    bslice_kernel<<<dim3(NH), 256, 0, stream>>>(grid, guide, inp, out);
}